// Round 15
// baseline (98.046 us; speedup 1.0000x reference)
//
#include <hip/hip_runtime.h>

// SpectralConv2dRealFreq: B=16, Cin=Cout=64, H=W=128, modes=33 (k in [-16,16])
// out = Re( iDFT2_trunc( (DFT2_trunc(x)) * (wr + i*wi) ) ), separable 1/sqrt(N) DFTs.
//
// Round 15: round-14 fat-load vmix with the m=1088 edge fix.
//   Bug was: pair-load base clamped 1088->1086, corrupting the last mode.
//   Fix: base = min(m,1088); second weight element loaded from offset
//   (m<1088)?1:0 (never OOB; value only feeds the discarded 1089 pad slot).
//   fwd zeroes X2u pad entries. Everything else identical to round 14.

#define NB   16
#define NC   64
#define NO   64
#define NH   128
#define NW   128
#define NM   33
#define WMODE (NM*NM)    // 1089 linear modes
#define MPAD  1092       // Kbf mode stride
#define XPAD  1092       // X2u mode stride (uint2-aligned)
#define NIMG 1024

typedef __attribute__((ext_vector_type(8))) short s8v;   // 8 bf16 (4 VGPRs)
typedef __attribute__((ext_vector_type(4))) float f4v;   // MFMA accumulator

__device__ inline unsigned short f2bf(float f) {
  union { float f; unsigned u; } v; v.f = f;
  unsigned r = (v.u + 0x7FFFu + ((v.u >> 16) & 1u)) >> 16;   // RNE
  return (unsigned short)r;
}

__device__ inline float bflo(unsigned u) {
  union { unsigned u; float f; } cv; cv.u = u << 16; return cv.f;
}
__device__ inline float bfhi(unsigned u) {
  union { unsigned u; float f; } cv; cv.u = u & 0xFFFF0000u; return cv.f;
}

__device__ inline s8v pack8(float4 a, float4 b) {
  s8v r;
  r[0] = (short)f2bf(a.x); r[1] = (short)f2bf(a.y);
  r[2] = (short)f2bf(a.z); r[3] = (short)f2bf(a.w);
  r[4] = (short)f2bf(b.x); r[5] = (short)f2bf(b.y);
  r[6] = (short)f2bf(b.z); r[7] = (short)f2bf(b.w);
  return r;
}

__device__ inline uint2 pack4(f4v a) {
  uint2 p;
  p.x = (unsigned)f2bf(a[0]) | ((unsigned)f2bf(a[1]) << 16);
  p.y = (unsigned)f2bf(a[2]) | ((unsigned)f2bf(a[3]) << 16);
  return p;
}

// stacked-phase value: f in [0,33): cos row f; [33,66): sin row f-33; >=66: 0
__device__ inline unsigned short phase_bf(int f, int x) {
  if (f >= 66) return 0;
  int g = (f < 33) ? f : f - 33;
  int fr = (g <= 16) ? g : g + 95;          // signed freq mod 128
  int ph = (fr * x) & 127;                  // exact integer phase
  float ang = (float)ph * 0.04908738521234052f;   // 2*pi/128
  float v = ((f < 33) ? cosf(ang) : sinf(ang)) * 0.08838834764831845f;  // /sqrt(128)
  return f2bf(v);
}

// --------------------------------------------------- fragment-layout tables
__global__ __launch_bounds__(256) void spc_tables(short* __restrict__ T1,
                                                  short* __restrict__ T2,
                                                  short* __restrict__ T3,
                                                  short* __restrict__ T4) {
  int tid = blockIdx.x * 256 + threadIdx.x;
  if (tid >= 49152) return;
  int f, x; short* dst;
  if (tid < 10240) {
    int e = tid & 7, l = (tid >> 3) & 63, q = tid >> 9;     // q = ks*5+jt
    int ks = q / 5, jt = q - 5 * ks;
    f = jt * 16 + (l & 15); x = ks * 32 + (l >> 4) * 8 + e; dst = T1 + tid;
  } else if (tid < 20480) {
    int u = tid - 10240;
    int e = u & 7, l = (u >> 3) & 63, q = u >> 9;           // q = it*4+ks
    int it = q >> 2, ks = q & 3;
    f = it * 16 + (l & 15); x = ks * 32 + (l >> 4) * 8 + e; dst = T2 + u;
  } else if (tid < 36864) {
    int u = tid - 20480;
    int e = u & 7, l = (u >> 3) & 63, q = u >> 9;           // q = (cs*2+ks)*8+mt
    int cs = q >> 4, ks = (q >> 3) & 1, mt = q & 7;
    int j = ks * 32 + (l >> 4) * 8 + e;
    f = (j < 33) ? cs * 33 + j : 66;
    x = mt * 16 + (l & 15); dst = T3 + u;
  } else {
    int u = tid - 36864;
    int e = u & 7, l = (u >> 3) & 63, q = u >> 9;           // q = nt*3+ks
    int nt = q / 3, ks = q - 3 * nt;
    int i2 = ks * 32 + (l >> 4) * 8 + e;
    if (i2 < 48) f = (i2 < 33) ? i2 : 66;
    else         f = (i2 - 48 < 33) ? 33 + (i2 - 48) : 66;
    x = nt * 16 + (l & 15); dst = T4 + u;
  }
  *dst = (short)phase_bf(f, x);
}

// --------------------------------------------------------------- forward DFT
__global__ __launch_bounds__(256) void spc_fwd_mfma(const float* __restrict__ x,
                                                    const s8v* __restrict__ T1,
                                                    const s8v* __restrict__ T2,
                                                    unsigned* __restrict__ X2u) {
  __shared__ short Wt[80 * 128];   // W1T[j][n] bf16, granule-4 XOR swizzle
  __shared__ float Gs[80 * 84];    // G f32, stride 84
  const int t = threadIdx.x;
  const int l = t & 63;
  const int w = t >> 6;
  const int lr = l & 15;
  const int lg = l >> 4;
  const int img = blockIdx.x;
  const float* xp = x + (size_t)img * (NH * NW);

  // stage 1: W1[n][j] = sum_m x[n][m] * Fw[j][m]; tiles (nt=2w..2w+1, jt 0..4)
  for (int nn = 0; nn < 2; ++nn) {
    const int nt = 2 * w + nn;
    const float* xrow = xp + (nt * 16 + lr) * NW + lg * 8;
    s8v a[4];
#pragma unroll
    for (int ks = 0; ks < 4; ++ks) {
      float4 f0 = *reinterpret_cast<const float4*>(xrow + ks * 32);
      float4 f1 = *reinterpret_cast<const float4*>(xrow + ks * 32 + 4);
      a[ks] = pack8(f0, f1);
    }
#pragma unroll
    for (int jt = 0; jt < 5; ++jt) {
      f4v acc = {0.f, 0.f, 0.f, 0.f};
#pragma unroll
      for (int ks = 0; ks < 4; ++ks) {
        s8v b = T1[(ks * 5 + jt) * 64 + l];
        acc = __builtin_amdgcn_mfma_f32_16x16x32_bf16(a[ks], b, acc, 0, 0, 0);
      }
      int j = jt * 16 + lr;
      int g = ((nt * 16 + lg * 4) >> 2) ^ ((j & 7) << 2);
      *reinterpret_cast<uint2*>(&Wt[j * 128 + g * 4]) = pack4(acc);
    }
  }
  __syncthreads();

  // stage 2: G[i][j] = sum_n Fh[i][n] * W1[n][j]; 25 tiles round-robin
  for (int tix = w; tix < 25; tix += 4) {
    int it = tix / 5, j2 = tix - 5 * it;
    int jrow = j2 * 16 + lr;
    f4v acc = {0.f, 0.f, 0.f, 0.f};
#pragma unroll
    for (int ks = 0; ks < 4; ++ks) {
      s8v afr = T2[(it * 4 + ks) * 64 + l];
      int g = (ks * 8 + lg * 2) ^ ((jrow & 7) << 2);
      s8v b = *reinterpret_cast<const s8v*>(&Wt[jrow * 128 + g * 4]);
      acc = __builtin_amdgcn_mfma_f32_16x16x32_bf16(afr, b, acc, 0, 0, 0);
    }
    int gi = it * 16 + lg * 4;
#pragma unroll
    for (int r = 0; r < 4; ++r) Gs[(gi + r) * 84 + jrow] = acc[r];
  }
  __syncthreads();

  // epilogue: X2r = G11 - G22, X2i = -(G12 + G21); packed bf16 pair per mode
  unsigned* X2p = X2u + (size_t)img * XPAD;
  for (int idx = t; idx < WMODE; idx += 256) {
    int i = idx / 33, j = idx - 33 * i;
    float g11 = Gs[i * 84 + j];
    float g22 = Gs[(i + 33) * 84 + (j + 33)];
    float g12 = Gs[i * 84 + (j + 33)];
    float g21 = Gs[(i + 33) * 84 + j];
    X2p[idx] = (unsigned)f2bf(g11 - g22) | ((unsigned)f2bf(-(g12 + g21)) << 16);
  }
  if (t < XPAD - WMODE) X2p[WMODE + t] = 0u;   // zero pad entries 1089..1091
}

// ---------------------------------------------------------------- channel mix
// K[b,o,m] = sum_c X[b,c,m]*R[c,o,m]; lane = 2 modes; wave = b-pair;
// block = 2 o's x 128-mode chunk x b-half; grid (32, 9, 2) = 576 blocks.
// Per c-iteration a wave requests ~2 KB in 10 instructions (fat loads).
__global__ __launch_bounds__(256) void spc_vmix(const float* __restrict__ wr,
                                                const float* __restrict__ wi,
                                                const unsigned* __restrict__ X2u,
                                                short* __restrict__ Kbf) {
  const int t = threadIdx.x;
  const int ml = t & 63;
  const int w = t >> 6;              // wave 0..3
  const int o0 = blockIdx.x * 2;     // 32 o-pairs
  const int mch = blockIdx.y;        // 9 chunks of 128 modes
  const int bh = blockIdx.z;         // b half
  const int b0 = bh * 8 + w * 2;
  const int m = mch * 128 + ml * 2;
  const int mcl = (m > 1088) ? 1088 : m;   // clamped load base (even, valid)
  const int off1 = (m < 1088) ? 1 : 0;     // 2nd weight elem: never OOB; value
                                           // only feeds the discarded 1089 slot

  const float* wp0 = wr + (size_t)o0 * WMODE + mcl;
  const float* ip0 = wi + (size_t)o0 * WMODE + mcl;
  const unsigned* x0 = X2u + (size_t)((b0 + 0) * 64) * XPAD + mcl;
  const unsigned* x1 = X2u + (size_t)((b0 + 1) * 64) * XPAD + mcl;
  const size_t cW = (size_t)64 * WMODE;
  const size_t cX = (size_t)XPAD;

  float aR[2][2][2], aI[2][2][2];    // [b][o][mode]
#pragma unroll
  for (int j = 0; j < 2; ++j)
#pragma unroll
    for (int oo = 0; oo < 2; ++oo)
#pragma unroll
      for (int mm = 0; mm < 2; ++mm) { aR[j][oo][mm] = 0.f; aI[j][oo][mm] = 0.f; }

#pragma unroll 1
  for (int c2 = 0; c2 < 32; ++c2) {
    // batch 2 c's: 8 weight-pair loads + 4 X uint2 per c -> ~4 KB requested
    float wv[2][2][2], iv[2][2][2];      // [cb][o][mode]
    uint2 xv[2][2];                      // [cb][b]
#pragma unroll
    for (int cb = 0; cb < 2; ++cb) {
      const int c = c2 * 2 + cb;
#pragma unroll
      for (int oo = 0; oo < 2; ++oo) {
        const float* wp = wp0 + (size_t)c * cW + (size_t)oo * WMODE;
        const float* ip = ip0 + (size_t)c * cW + (size_t)oo * WMODE;
        wv[cb][oo][0] = wp[0]; wv[cb][oo][1] = wp[off1];
        iv[cb][oo][0] = ip[0]; iv[cb][oo][1] = ip[off1];
      }
      xv[cb][0] = *reinterpret_cast<const uint2*>(x0 + (size_t)c * cX);
      xv[cb][1] = *reinterpret_cast<const uint2*>(x1 + (size_t)c * cX);
    }
#pragma unroll
    for (int cb = 0; cb < 2; ++cb) {
#pragma unroll
      for (int j = 0; j < 2; ++j) {
        const unsigned um0 = j ? xv[cb][1].x : xv[cb][0].x;
        const unsigned um1 = j ? xv[cb][1].y : xv[cb][0].y;
        const float xr0 = bflo(um0), xi0 = bfhi(um0);
        const float xr1 = bflo(um1), xi1 = bfhi(um1);
#pragma unroll
        for (int oo = 0; oo < 2; ++oo) {
          aR[j][oo][0] = fmaf(xr0, wv[cb][oo][0], fmaf(-xi0, iv[cb][oo][0], aR[j][oo][0]));
          aI[j][oo][0] = fmaf(xr0, iv[cb][oo][0], fmaf( xi0, wv[cb][oo][0], aI[j][oo][0]));
          aR[j][oo][1] = fmaf(xr1, wv[cb][oo][1], fmaf(-xi1, iv[cb][oo][1], aR[j][oo][1]));
          aI[j][oo][1] = fmaf(xr1, iv[cb][oo][1], fmaf( xi1, wv[cb][oo][1], aI[j][oo][1]));
        }
      }
    }
  }

  if (m <= 1088) {
#pragma unroll
    for (int j = 0; j < 2; ++j)
#pragma unroll
      for (int oo = 0; oo < 2; ++oo) {
        size_t img = (size_t)(b0 + j) * 64 + o0 + oo;
        unsigned uR = (unsigned)f2bf(aR[j][oo][0]) | ((unsigned)f2bf(aR[j][oo][1]) << 16);
        unsigned uI = (unsigned)f2bf(aI[j][oo][0]) | ((unsigned)f2bf(aI[j][oo][1]) << 16);
        *reinterpret_cast<unsigned*>(Kbf + img * (2 * MPAD) + m) = uR;   // m=1088: 2nd half lands in pad (never read)
        *reinterpret_cast<unsigned*>(Kbf + img * (2 * MPAD) + MPAD + m) = uI;
      }
  }
}

// ---------------------------------------------------------------- inverse DFT
__global__ __launch_bounds__(256) void spc_inv_mfma(const short* __restrict__ Kbf,
                                                    const s8v* __restrict__ T3,
                                                    const s8v* __restrict__ T4,
                                                    float* __restrict__ out) {
  __shared__ short Kls2[2 * MPAD];  // per-image K slice (4368 B)
  __shared__ short Vt[128 * 128];   // stacked [T1; -T2] rows i'<96, [m][i'] swizzled
  const int t = threadIdx.x;
  const int l = t & 63;
  const int w = t >> 6;
  const int lr = l & 15;
  const int lg = l >> 4;
  const int img = blockIdx.x;

  {
    const uint4* src = reinterpret_cast<const uint4*>(Kbf + (size_t)img * (2 * MPAD));
    uint4* dstl = reinterpret_cast<uint4*>(Kls2);
    for (int idx = t; idx < 273; idx += 256) dstl[idx] = src[idx];
  }
  __syncthreads();

  // build Kr/Ki A-fragments: [ri][it<3][ks<2], row i=it*16+lr, k j=ks*32+lg*8+e
  s8v fr[2][3][2];
#pragma unroll
  for (int ri2 = 0; ri2 < 2; ++ri2)
#pragma unroll
    for (int it = 0; it < 3; ++it)
#pragma unroll
      for (int ks = 0; ks < 2; ++ks) {
        const int i = it * 16 + lr;
#pragma unroll
        for (int e = 0; e < 8; ++e) {
          const int j = ks * 32 + lg * 8 + e;
          unsigned short v = (i < 33 && j < 33)
              ? (unsigned short)Kls2[ri2 * MPAD + i * 33 + j] : (unsigned short)0;
          fr[ri2][it][ks][e] = (short)v;
        }
      }

  // stage 1: T1[i][m] = Kr·Cw − Ki·Sw ; T2 = Ki·Cw + Kr·Sw ; store [T1; −T2]
  for (int mm = 0; mm < 2; ++mm) {
    const int mt = w * 2 + mm;
    const int m = mt * 16 + lr;
    s8v cw[2], sw[2], nsw[2];
#pragma unroll
    for (int ks = 0; ks < 2; ++ks) {
      cw[ks] = T3[((0 * 2 + ks) * 8 + mt) * 64 + l];
      sw[ks] = T3[((1 * 2 + ks) * 8 + mt) * 64 + l];
#pragma unroll
      for (int e = 0; e < 8; ++e)
        nsw[ks][e] = (short)(((unsigned short)sw[ks][e]) ^ 0x8000u);
    }
#pragma unroll
    for (int it = 0; it < 3; ++it) {
      f4v t1 = {0.f, 0.f, 0.f, 0.f}, t2 = {0.f, 0.f, 0.f, 0.f};
#pragma unroll
      for (int ks = 0; ks < 2; ++ks) {
        t1 = __builtin_amdgcn_mfma_f32_16x16x32_bf16(fr[0][it][ks], cw[ks],  t1, 0, 0, 0);
        t1 = __builtin_amdgcn_mfma_f32_16x16x32_bf16(fr[1][it][ks], nsw[ks], t1, 0, 0, 0);
        t2 = __builtin_amdgcn_mfma_f32_16x16x32_bf16(fr[1][it][ks], cw[ks],  t2, 0, 0, 0);
        t2 = __builtin_amdgcn_mfma_f32_16x16x32_bf16(fr[0][it][ks], sw[ks],  t2, 0, 0, 0);
      }
      const int base1 = it * 16 + lg * 4;
      const int g1 = (base1 >> 2) ^ ((m & 7) << 2);
      *reinterpret_cast<uint2*>(&Vt[m * 128 + g1 * 4]) = pack4(t1);
      f4v nt2v = {-t2[0], -t2[1], -t2[2], -t2[3]};
      const int g2 = ((48 + base1) >> 2) ^ ((m & 7) << 2);
      *reinterpret_cast<uint2*>(&Vt[m * 128 + g2 * 4]) = pack4(nt2v);
    }
  }
  __syncthreads();

  // stage 2: out[n][m] = sum_{i'<96} A2[n][i'] · Vt[i'][m]
  float* op = out + (size_t)img * (NH * NW);
  for (int nn = 0; nn < 2; ++nn) {
    const int nt = w * 2 + nn;
    s8v a[3];
#pragma unroll
    for (int ks = 0; ks < 3; ++ks) a[ks] = T4[(nt * 3 + ks) * 64 + l];
    for (int mt = 0; mt < 8; ++mt) {
      const int m = mt * 16 + lr;
      f4v acc = {0.f, 0.f, 0.f, 0.f};
#pragma unroll
      for (int ks = 0; ks < 3; ++ks) {
        const int g = (ks * 8 + lg * 2) ^ ((m & 7) << 2);
        s8v bb = *reinterpret_cast<const s8v*>(&Vt[m * 128 + g * 4]);
        acc = __builtin_amdgcn_mfma_f32_16x16x32_bf16(a[ks], bb, acc, 0, 0, 0);
      }
      const int n = nt * 16 + lg * 4;
#pragma unroll
      for (int r = 0; r < 4; ++r) op[(n + r) * NW + m] = acc[r];
    }
  }
}

// ---------------------------------------------------------------- launch
extern "C" void kernel_launch(void* const* d_in, const int* in_sizes, int n_in,
                              void* d_out, int out_size, void* d_ws, size_t ws_size,
                              hipStream_t stream) {
  const float* x  = (const float*)d_in[0];
  const float* wr = (const float*)d_in[1];
  const float* wi = (const float*)d_in[2];
  float* out = (float*)d_out;

  char* ws = (char*)d_ws;
  short* T1 = (short*)(ws);                    // 20480 B
  short* T2 = (short*)(ws + 20480);            // 20480 B
  short* T3 = (short*)(ws + 40960);            // 32768 B
  short* T4 = (short*)(ws + 73728);            // 24576 B  -> 98304
  unsigned* X2u = (unsigned*)(ws + 98304);     // 1024*1092*4 = 4,472,832 -> 4,571,136
  short* Kbf = (short*)(ws + 4571136);         // 1024*2184*2 = 4,472,832 -> 9,043,968
  // total ~9.0 MB

  hipLaunchKernelGGL(spc_tables, dim3(192), dim3(256), 0, stream, T1, T2, T3, T4);
  hipLaunchKernelGGL(spc_fwd_mfma, dim3(NIMG), dim3(256), 0, stream,
                     x, (const s8v*)T1, (const s8v*)T2, X2u);
  hipLaunchKernelGGL(spc_vmix, dim3(32, 9, 2), dim3(256), 0, stream,
                     wr, wi, X2u, Kbf);
  hipLaunchKernelGGL(spc_inv_mfma, dim3(NIMG), dim3(256), 0, stream,
                     Kbf, (const s8v*)T3, (const s8v*)T4, out);
}

// Round 16
// 72.107 us; speedup vs baseline: 1.3597x; 1.3597x over previous
//
#include <hip/hip_runtime.h>

// SpectralConv2dRealFreq: B=16, Cin=Cout=64, H=W=128, modes=33 (k in [-16,16])
// out = Re( iDFT2_trunc( (DFT2_trunc(x)) * (wr + i*wi) ) ), separable 1/sqrt(N) DFTs.
//
// Round 16: R11 vmix + c-split x2 (concurrency A/B).
//   All vmix variants (R9/R11/R12/R15) capped at ~0.85 TB/s with BW tracking
//   wave-count x ~3-loads-in-flight; grid was demand-starved (<=18 waves/CU).
//   Now: grid (32,18,2) = 1152 blocks x 8 waves = 36 waves/CU demand.
//   Each c-half writes f32 partials Kp[half]; inv sums halves, rounds to bf16
//   once (numerics unchanged). Everything else identical to round 11.

#define NB   16
#define NC   64
#define NO   64
#define NH   128
#define NW   128
#define NM   33
#define WMODE (NM*NM)    // 1089 linear modes
#define MPAD  1092       // K mode stride
#define NIMG 1024

typedef __attribute__((ext_vector_type(8))) short s8v;   // 8 bf16 (4 VGPRs)
typedef __attribute__((ext_vector_type(4))) float f4v;   // MFMA accumulator

__device__ inline unsigned short f2bf(float f) {
  union { float f; unsigned u; } v; v.f = f;
  unsigned r = (v.u + 0x7FFFu + ((v.u >> 16) & 1u)) >> 16;   // RNE
  return (unsigned short)r;
}

__device__ inline float bflo(unsigned u) {
  union { unsigned u; float f; } cv; cv.u = u << 16; return cv.f;
}
__device__ inline float bfhi(unsigned u) {
  union { unsigned u; float f; } cv; cv.u = u & 0xFFFF0000u; return cv.f;
}

__device__ inline s8v pack8(float4 a, float4 b) {
  s8v r;
  r[0] = (short)f2bf(a.x); r[1] = (short)f2bf(a.y);
  r[2] = (short)f2bf(a.z); r[3] = (short)f2bf(a.w);
  r[4] = (short)f2bf(b.x); r[5] = (short)f2bf(b.y);
  r[6] = (short)f2bf(b.z); r[7] = (short)f2bf(b.w);
  return r;
}

__device__ inline uint2 pack4(f4v a) {
  uint2 p;
  p.x = (unsigned)f2bf(a[0]) | ((unsigned)f2bf(a[1]) << 16);
  p.y = (unsigned)f2bf(a[2]) | ((unsigned)f2bf(a[3]) << 16);
  return p;
}

// stacked-phase value: f in [0,33): cos row f; [33,66): sin row f-33; >=66: 0
__device__ inline unsigned short phase_bf(int f, int x) {
  if (f >= 66) return 0;
  int g = (f < 33) ? f : f - 33;
  int fr = (g <= 16) ? g : g + 95;          // signed freq mod 128
  int ph = (fr * x) & 127;                  // exact integer phase
  float ang = (float)ph * 0.04908738521234052f;   // 2*pi/128
  float v = ((f < 33) ? cosf(ang) : sinf(ang)) * 0.08838834764831845f;  // /sqrt(128)
  return f2bf(v);
}

// --------------------------------------------------- fragment-layout tables
__global__ __launch_bounds__(256) void spc_tables(short* __restrict__ T1,
                                                  short* __restrict__ T2,
                                                  short* __restrict__ T3,
                                                  short* __restrict__ T4) {
  int tid = blockIdx.x * 256 + threadIdx.x;
  if (tid >= 49152) return;
  int f, x; short* dst;
  if (tid < 10240) {
    int e = tid & 7, l = (tid >> 3) & 63, q = tid >> 9;     // q = ks*5+jt
    int ks = q / 5, jt = q - 5 * ks;
    f = jt * 16 + (l & 15); x = ks * 32 + (l >> 4) * 8 + e; dst = T1 + tid;
  } else if (tid < 20480) {
    int u = tid - 10240;
    int e = u & 7, l = (u >> 3) & 63, q = u >> 9;           // q = it*4+ks
    int it = q >> 2, ks = q & 3;
    f = it * 16 + (l & 15); x = ks * 32 + (l >> 4) * 8 + e; dst = T2 + u;
  } else if (tid < 36864) {
    int u = tid - 20480;
    int e = u & 7, l = (u >> 3) & 63, q = u >> 9;           // q = (cs*2+ks)*8+mt
    int cs = q >> 4, ks = (q >> 3) & 1, mt = q & 7;
    int j = ks * 32 + (l >> 4) * 8 + e;
    f = (j < 33) ? cs * 33 + j : 66;
    x = mt * 16 + (l & 15); dst = T3 + u;
  } else {
    int u = tid - 36864;
    int e = u & 7, l = (u >> 3) & 63, q = u >> 9;           // q = nt*3+ks
    int nt = q / 3, ks = q - 3 * nt;
    int i2 = ks * 32 + (l >> 4) * 8 + e;
    if (i2 < 48) f = (i2 < 33) ? i2 : 66;
    else         f = (i2 - 48 < 33) ? 33 + (i2 - 48) : 66;
    x = nt * 16 + (l & 15); dst = T4 + u;
  }
  *dst = (short)phase_bf(f, x);
}

// --------------------------------------------------------------- forward DFT
__global__ __launch_bounds__(256) void spc_fwd_mfma(const float* __restrict__ x,
                                                    const s8v* __restrict__ T1,
                                                    const s8v* __restrict__ T2,
                                                    unsigned* __restrict__ X2u) {
  __shared__ short Wt[80 * 128];   // W1T[j][n] bf16, granule-4 XOR swizzle
  __shared__ float Gs[80 * 84];    // G f32, stride 84
  const int t = threadIdx.x;
  const int l = t & 63;
  const int w = t >> 6;
  const int lr = l & 15;
  const int lg = l >> 4;
  const int img = blockIdx.x;
  const float* xp = x + (size_t)img * (NH * NW);

  // stage 1: W1[n][j] = sum_m x[n][m] * Fw[j][m]; tiles (nt=2w..2w+1, jt 0..4)
  for (int nn = 0; nn < 2; ++nn) {
    const int nt = 2 * w + nn;
    const float* xrow = xp + (nt * 16 + lr) * NW + lg * 8;
    s8v a[4];
#pragma unroll
    for (int ks = 0; ks < 4; ++ks) {
      float4 f0 = *reinterpret_cast<const float4*>(xrow + ks * 32);
      float4 f1 = *reinterpret_cast<const float4*>(xrow + ks * 32 + 4);
      a[ks] = pack8(f0, f1);
    }
#pragma unroll
    for (int jt = 0; jt < 5; ++jt) {
      f4v acc = {0.f, 0.f, 0.f, 0.f};
#pragma unroll
      for (int ks = 0; ks < 4; ++ks) {
        s8v b = T1[(ks * 5 + jt) * 64 + l];
        acc = __builtin_amdgcn_mfma_f32_16x16x32_bf16(a[ks], b, acc, 0, 0, 0);
      }
      int j = jt * 16 + lr;
      int g = ((nt * 16 + lg * 4) >> 2) ^ ((j & 7) << 2);
      *reinterpret_cast<uint2*>(&Wt[j * 128 + g * 4]) = pack4(acc);
    }
  }
  __syncthreads();

  // stage 2: G[i][j] = sum_n Fh[i][n] * W1[n][j]; 25 tiles round-robin
  for (int tix = w; tix < 25; tix += 4) {
    int it = tix / 5, j2 = tix - 5 * it;
    int jrow = j2 * 16 + lr;
    f4v acc = {0.f, 0.f, 0.f, 0.f};
#pragma unroll
    for (int ks = 0; ks < 4; ++ks) {
      s8v afr = T2[(it * 4 + ks) * 64 + l];
      int g = (ks * 8 + lg * 2) ^ ((jrow & 7) << 2);
      s8v b = *reinterpret_cast<const s8v*>(&Wt[jrow * 128 + g * 4]);
      acc = __builtin_amdgcn_mfma_f32_16x16x32_bf16(afr, b, acc, 0, 0, 0);
    }
    int gi = it * 16 + lg * 4;
#pragma unroll
    for (int r = 0; r < 4; ++r) Gs[(gi + r) * 84 + jrow] = acc[r];
  }
  __syncthreads();

  // epilogue: X2r = G11 - G22, X2i = -(G12 + G21); packed bf16 pair per mode
  unsigned* X2p = X2u + (size_t)img * WMODE;
  for (int idx = t; idx < WMODE; idx += 256) {
    int i = idx / 33, j = idx - 33 * i;
    float g11 = Gs[i * 84 + j];
    float g22 = Gs[(i + 33) * 84 + (j + 33)];
    float g12 = Gs[i * 84 + (j + 33)];
    float g21 = Gs[(i + 33) * 84 + j];
    X2p[idx] = (unsigned)f2bf(g11 - g22) | ((unsigned)f2bf(-(g12 + g21)) << 16);
  }
}

// ---------------------------------------------------------------- channel mix
// K[b,o,m] = sum_c X[b,c,m]*R[c,o,m] — elementwise along m for fixed (c,o).
// lane = m; wave = b-pair (8 waves); block = 2 o's x 64-mode chunk x c-half.
// grid (32, 18, 2) = 1152 blocks = 36 waves/CU demand (concurrency fix).
// Partials written in f32 to Kp[half][img][ri][MPAD]; inv sums halves.
__global__ __launch_bounds__(512) void spc_vmix(const float* __restrict__ wr,
                                                const float* __restrict__ wi,
                                                const unsigned* __restrict__ X2u,
                                                float* __restrict__ Kp) {
  const int t = threadIdx.x;
  const int ml = t & 63;
  const int w = t >> 6;              // wave 0..7 -> b pair {2w, 2w+1}
  const int b0 = w * 2;
  const int o0 = blockIdx.x * 2;     // 32 o-tiles
  const int m0 = blockIdx.y * 64;    // 18 m-chunks
  const int ch = blockIdx.z;         // c half: c in [ch*32, ch*32+32)
  const int c_base = ch * 32;
  const int m = m0 + ml;
  const int mc = (m > 1088) ? 1088 : m;   // clamp for loads (edge chunk)

  const float* wrp = wr + (size_t)(c_base * 64 + o0) * WMODE + mc;
  const float* wip = wi + (size_t)(c_base * 64 + o0) * WMODE + mc;
  const unsigned* xp = X2u + (size_t)(b0 * 64 + c_base) * WMODE + mc;
  const size_t cstepW = (size_t)64 * WMODE;   // c stride in weights

  float aR[2][2], aI[2][2];
#pragma unroll
  for (int j = 0; j < 2; ++j)
#pragma unroll
    for (int oo = 0; oo < 2; ++oo) { aR[j][oo] = 0.f; aI[j][oo] = 0.f; }

#pragma unroll 1   // bounded load window (round-10 lesson: full unroll -> spill)
  for (int c4 = 0; c4 < 8; ++c4) {
    // batch 24 independent loads (16 weight + 8 X) before any use
    float wrv[4][2], wiv[4][2];
    unsigned u[4][2];
#pragma unroll
    for (int q = 0; q < 4; ++q) {
      const int c = c4 * 4 + q;
#pragma unroll
      for (int oo = 0; oo < 2; ++oo) {
        wrv[q][oo] = wrp[(size_t)c * cstepW + (size_t)oo * WMODE];
        wiv[q][oo] = wip[(size_t)c * cstepW + (size_t)oo * WMODE];
      }
#pragma unroll
      for (int j = 0; j < 2; ++j)
        u[q][j] = xp[(size_t)(j * 64 + c) * WMODE];
    }
#pragma unroll
    for (int q = 0; q < 4; ++q) {
#pragma unroll
      for (int j = 0; j < 2; ++j) {
        const float xr_ = bflo(u[q][j]);
        const float xi_ = bfhi(u[q][j]);
#pragma unroll
        for (int oo = 0; oo < 2; ++oo) {
          aR[j][oo] = fmaf(xr_, wrv[q][oo], fmaf(-xi_, wiv[q][oo], aR[j][oo]));
          aI[j][oo] = fmaf(xr_, wiv[q][oo], fmaf( xi_, wrv[q][oo], aI[j][oo]));
        }
      }
    }
  }

  if (m < WMODE) {
#pragma unroll
    for (int j = 0; j < 2; ++j)
#pragma unroll
      for (int oo = 0; oo < 2; ++oo) {
        size_t img = (size_t)(b0 + j) * 64 + o0 + oo;
        float* dst = Kp + ((size_t)ch * NIMG + img) * (2 * MPAD);
        dst[m]        = aR[j][oo];
        dst[MPAD + m] = aI[j][oo];
      }
  }
}

// ---------------------------------------------------------------- inverse DFT
__global__ __launch_bounds__(256) void spc_inv_mfma(const float* __restrict__ Kp,
                                                    const s8v* __restrict__ T3,
                                                    const s8v* __restrict__ T4,
                                                    float* __restrict__ out) {
  __shared__ short Kls2[2 * MPAD];  // per-image K slice bf16 (4368 B)
  __shared__ short Vt[128 * 128];   // stacked [T1; -T2] rows i'<96, [m][i'] swizzled
  const int t = threadIdx.x;
  const int l = t & 63;
  const int w = t >> 6;
  const int lr = l & 15;
  const int lg = l >> 4;
  const int img = blockIdx.x;

  {
    // sum the two c-half partials (f32), round to bf16 once
    const float4* p0 = reinterpret_cast<const float4*>(
        Kp + ((size_t)0 * NIMG + img) * (2 * MPAD));
    const float4* p1 = reinterpret_cast<const float4*>(
        Kp + ((size_t)1 * NIMG + img) * (2 * MPAD));
    for (int idx = t; idx < 546; idx += 256) {   // 546*4 = 2184 = 2*MPAD
      float4 a = p0[idx];
      float4 b = p1[idx];
      uint2 u;
      u.x = (unsigned)f2bf(a.x + b.x) | ((unsigned)f2bf(a.y + b.y) << 16);
      u.y = (unsigned)f2bf(a.z + b.z) | ((unsigned)f2bf(a.w + b.w) << 16);
      *reinterpret_cast<uint2*>(&Kls2[idx * 4]) = u;
    }
  }
  __syncthreads();

  // build Kr/Ki A-fragments: [ri][it<3][ks<2], row i=it*16+lr, k j=ks*32+lg*8+e
  s8v fr[2][3][2];
#pragma unroll
  for (int ri2 = 0; ri2 < 2; ++ri2)
#pragma unroll
    for (int it = 0; it < 3; ++it)
#pragma unroll
      for (int ks = 0; ks < 2; ++ks) {
        const int i = it * 16 + lr;
#pragma unroll
        for (int e = 0; e < 8; ++e) {
          const int j = ks * 32 + lg * 8 + e;
          unsigned short v = (i < 33 && j < 33)
              ? (unsigned short)Kls2[ri2 * MPAD + i * 33 + j] : (unsigned short)0;
          fr[ri2][it][ks][e] = (short)v;
        }
      }

  // stage 1: T1[i][m] = Kr·Cw − Ki·Sw ; T2 = Ki·Cw + Kr·Sw ; store [T1; −T2]
  for (int mm = 0; mm < 2; ++mm) {
    const int mt = w * 2 + mm;
    const int m = mt * 16 + lr;
    s8v cw[2], sw[2], nsw[2];
#pragma unroll
    for (int ks = 0; ks < 2; ++ks) {
      cw[ks] = T3[((0 * 2 + ks) * 8 + mt) * 64 + l];
      sw[ks] = T3[((1 * 2 + ks) * 8 + mt) * 64 + l];
#pragma unroll
      for (int e = 0; e < 8; ++e)
        nsw[ks][e] = (short)(((unsigned short)sw[ks][e]) ^ 0x8000u);
    }
#pragma unroll
    for (int it = 0; it < 3; ++it) {
      f4v t1 = {0.f, 0.f, 0.f, 0.f}, t2 = {0.f, 0.f, 0.f, 0.f};
#pragma unroll
      for (int ks = 0; ks < 2; ++ks) {
        t1 = __builtin_amdgcn_mfma_f32_16x16x32_bf16(fr[0][it][ks], cw[ks],  t1, 0, 0, 0);
        t1 = __builtin_amdgcn_mfma_f32_16x16x32_bf16(fr[1][it][ks], nsw[ks], t1, 0, 0, 0);
        t2 = __builtin_amdgcn_mfma_f32_16x16x32_bf16(fr[1][it][ks], cw[ks],  t2, 0, 0, 0);
        t2 = __builtin_amdgcn_mfma_f32_16x16x32_bf16(fr[0][it][ks], sw[ks],  t2, 0, 0, 0);
      }
      const int base1 = it * 16 + lg * 4;
      const int g1 = (base1 >> 2) ^ ((m & 7) << 2);
      *reinterpret_cast<uint2*>(&Vt[m * 128 + g1 * 4]) = pack4(t1);
      f4v nt2v = {-t2[0], -t2[1], -t2[2], -t2[3]};
      const int g2 = ((48 + base1) >> 2) ^ ((m & 7) << 2);
      *reinterpret_cast<uint2*>(&Vt[m * 128 + g2 * 4]) = pack4(nt2v);
    }
  }
  __syncthreads();

  // stage 2: out[n][m] = sum_{i'<96} A2[n][i'] · Vt[i'][m]
  float* op = out + (size_t)img * (NH * NW);
  for (int nn = 0; nn < 2; ++nn) {
    const int nt = w * 2 + nn;
    s8v a[3];
#pragma unroll
    for (int ks = 0; ks < 3; ++ks) a[ks] = T4[(nt * 3 + ks) * 64 + l];
    for (int mt = 0; mt < 8; ++mt) {
      const int m = mt * 16 + lr;
      f4v acc = {0.f, 0.f, 0.f, 0.f};
#pragma unroll
      for (int ks = 0; ks < 3; ++ks) {
        const int g = (ks * 8 + lg * 2) ^ ((m & 7) << 2);
        s8v bb = *reinterpret_cast<const s8v*>(&Vt[m * 128 + g * 4]);
        acc = __builtin_amdgcn_mfma_f32_16x16x32_bf16(a[ks], bb, acc, 0, 0, 0);
      }
      const int n = nt * 16 + lg * 4;
#pragma unroll
      for (int r = 0; r < 4; ++r) op[(n + r) * NW + m] = acc[r];
    }
  }
}

// ---------------------------------------------------------------- launch
extern "C" void kernel_launch(void* const* d_in, const int* in_sizes, int n_in,
                              void* d_out, int out_size, void* d_ws, size_t ws_size,
                              hipStream_t stream) {
  const float* x  = (const float*)d_in[0];
  const float* wr = (const float*)d_in[1];
  const float* wi = (const float*)d_in[2];
  float* out = (float*)d_out;

  char* ws = (char*)d_ws;
  short* T1 = (short*)(ws);                    // 20480 B
  short* T2 = (short*)(ws + 20480);            // 20480 B
  short* T3 = (short*)(ws + 40960);            // 32768 B
  short* T4 = (short*)(ws + 73728);            // 24576 B  -> 98304
  unsigned* X2u = (unsigned*)(ws + 98304);     // 1024*1089*4 = 4,460,544 -> 4,558,848
  float* Kp = (float*)(ws + 4558848);          // 2*1024*2184*4 = 17,891,328 -> 22,450,176
  // total ~22.5 MB

  hipLaunchKernelGGL(spc_tables, dim3(192), dim3(256), 0, stream, T1, T2, T3, T4);
  hipLaunchKernelGGL(spc_fwd_mfma, dim3(NIMG), dim3(256), 0, stream,
                     x, (const s8v*)T1, (const s8v*)T2, X2u);
  hipLaunchKernelGGL(spc_vmix, dim3(32, 18, 2), dim3(512), 0, stream,
                     wr, wi, X2u, Kp);
  hipLaunchKernelGGL(spc_inv_mfma, dim3(NIMG), dim3(256), 0, stream,
                     Kp, (const s8v*)T3, (const s8v*)T4, out);
}